// Round 7
// baseline (418.814 us; speedup 1.0000x reference)
//
#include <hip/hip_runtime.h>
#include <hip/hip_bf16.h>

#define HD 128

typedef unsigned int u32;
typedef unsigned short u16;
typedef __attribute__((ext_vector_type(8))) short short8;   // 8 bf16 (4 VGPRs)
typedef __attribute__((ext_vector_type(4))) float f32x4;    // MFMA C/D

__device__ __forceinline__ float bf2f(u16 u) {
    return __uint_as_float(((u32)u) << 16);
}
__device__ __forceinline__ u16 f2bf(float f) {
    u32 u = __float_as_uint(f);
    u32 r = (u + 0x7fffu + ((u >> 16) & 1u)) >> 16;   // RNE
    return (u16)r;
}
// packed RNE f32x2 -> bf16x2; lo -> low 16 bits
__device__ __forceinline__ u32 pk2bf(float lo, float hi) {
    __hip_bfloat162 h = __float22bfloat162_rn(make_float2(lo, hi));
    union { __hip_bfloat162 h; u32 u; } cv; cv.h = h;
    return cv.u;
}
// packed bf16x2 multiply (RNE)
__device__ __forceinline__ u32 hmul2(u32 a, u32 b) {
    union { u32 u; __hip_bfloat162 h; } x, y, r;
    x.u = a; y.u = b;
    r.h = __hmul2(x.h, y.h);
    return r.u;
}
__device__ __forceinline__ float ldf(const void* p, size_t i, bool f32m) {
    return f32m ? ((const float*)p)[i] : bf2f(((const u16*)p)[i]);
}
// XOR-swizzled halfword index into a 64x128 bf16 LDS tile (16B-block swizzle).
__device__ __forceinline__ int swz(int row, int col) {
    return row * 128 + ((((col >> 3) ^ (row & 7)) << 3) | (col & 7));
}
__device__ __forceinline__ void acc8_bf16(uint4 v, float* a) {
    a[0] += __uint_as_float(v.x << 16); a[1] += __uint_as_float(v.x & 0xffff0000u);
    a[2] += __uint_as_float(v.y << 16); a[3] += __uint_as_float(v.y & 0xffff0000u);
    a[4] += __uint_as_float(v.z << 16); a[5] += __uint_as_float(v.z & 0xffff0000u);
    a[6] += __uint_as_float(v.w << 16); a[7] += __uint_as_float(v.w & 0xffff0000u);
}

// ---- dtype detector (parallel) ----
__global__ void detect_mode(const u32* __restrict__ x, int* __restrict__ mode) {
    __shared__ int cnt_s;
    if (threadIdx.x == 0) cnt_s = 0;
    __syncthreads();
    u32 e = (x[threadIdx.x] >> 23) & 0xFFu;
    if (e >= 90u && e < 170u) atomicAdd(&cnt_s, 1);
    __syncthreads();
    if (threadIdx.x == 0) mode[0] = (cnt_s >= 128) ? 1 : 0;
}

// ---- materialize bf16 X into workspace (convert f32, or plain copy bf16) ----
__global__ void cast_x(const void* __restrict__ x, u16* __restrict__ xb,
                       const int* __restrict__ gmode, int total8) {
    const bool f32m = gmode[0] != 0;
    int i = blockIdx.x * 256 + threadIdx.x;
    int stride = gridDim.x * 256;
    if (f32m) {
        for (; i < total8; i += stride) {
            const float* p = (const float*)x + (size_t)i * 8;
            float4 v0 = *(const float4*)p, v1 = *(const float4*)(p + 4);
            uint4 o;
            o.x = pk2bf(v0.x, v0.y); o.y = pk2bf(v0.z, v0.w);
            o.z = pk2bf(v1.x, v1.y); o.w = pk2bf(v1.z, v1.w);
            *(uint4*)(xb + (size_t)i * 8) = o;
        }
    } else {
        for (; i < total8; i += stride) {
            *(uint4*)(xb + (size_t)i * 8) =
                *(const uint4*)((const u16*)x + (size_t)i * 8);
        }
    }
}

// ---- pack six 128x128 weight matrices into MFMA fragment order (bf16) ----
__global__ void pack_w6(const void* __restrict__ W0, const void* __restrict__ W1,
                        const void* __restrict__ W2, const void* __restrict__ W3,
                        const void* __restrict__ W4, const void* __restrict__ W5,
                        u16* __restrict__ out, const int* __restrict__ gmode) {
    const bool f32m = gmode[0] != 0;
    int gid = blockIdx.x * 256 + threadIdx.x;
    if (gid >= 6 * 16384) return;
    int sel = gid >> 14, idx = gid & 16383;
    const void* W = sel == 0 ? W0 : sel == 1 ? W1 : sel == 2 ? W2 :
                    sel == 3 ? W3 : sel == 4 ? W4 : W5;
    int j = idx & 7, lane = (idx >> 3) & 63, ks = (idx >> 9) & 3, nt = idx >> 11;
    int k = ks * 32 + (lane >> 4) * 8 + j;
    int n = nt * 16 + (lane & 15);
    out[gid] = f2bf(ldf(W, (size_t)k * HD + n, f32m));
}

// ================= CSR build ===========
__global__ void cnt_count(const int* __restrict__ dst, int* __restrict__ cnt, int e) {
    int i = blockIdx.x * 256 + threadIdx.x;
    if (i < e) atomicAdd(&cnt[dst[i]], 1);
}

// histogram over SRC of the combined pos+neg pair list
__global__ void cnt2_count(const int* __restrict__ ps, const int* __restrict__ ns,
                           int ep, int te, int* __restrict__ cnt) {
    int i = blockIdx.x * 256 + threadIdx.x;
    if (i >= te) return;
    int s = (i < ep) ? ps[i] : ns[i - ep];
    atomicAdd(&cnt[s], 1);
}

__global__ void scan_blocks(const int* __restrict__ cnt, int* __restrict__ rowptr,
                            int* __restrict__ bsum, int n) {
    __shared__ int s[256];
    int t = threadIdx.x, gid = blockIdx.x * 256 + t;
    int v = (gid < n) ? cnt[gid] : 0;
    s[t] = v; __syncthreads();
    #pragma unroll
    for (int off = 1; off < 256; off <<= 1) {
        int x = (t >= off) ? s[t - off] : 0;
        __syncthreads();
        s[t] += x;
        __syncthreads();
    }
    if (gid < n) rowptr[gid] = s[t] - v;
    if (t == 255) bsum[blockIdx.x] = s[255];
}

__global__ void scan_bsum(int* __restrict__ bsum, int nb) {
    __shared__ int s[1024];
    __shared__ int carry;
    int t = threadIdx.x;
    if (t == 0) carry = 0;
    __syncthreads();
    for (int base = 0; base < nb; base += 1024) {
        int i = base + t;
        int v = (i < nb) ? bsum[i] : 0;
        s[t] = v; __syncthreads();
        #pragma unroll
        for (int off = 1; off < 1024; off <<= 1) {
            int x = (t >= off) ? s[t - off] : 0;
            __syncthreads();
            s[t] += x;
            __syncthreads();
        }
        if (i < nb) bsum[i] = carry + s[t] - v;
        __syncthreads();
        if (t == 0) carry += s[1023];
        __syncthreads();
    }
}

// rowptr finalize + cursor init (cur = rowptr)
__global__ void scan_add(int* __restrict__ rowptr, const int* __restrict__ bsum,
                         int* __restrict__ cur, int n, int e) {
    int gid = blockIdx.x * 256 + threadIdx.x;
    if (gid < n) {
        int v = rowptr[gid] + bsum[blockIdx.x];
        rowptr[gid] = v;
        cur[gid] = v;
    } else if (gid == n) {
        rowptr[n] = e;
    }
}

__global__ void csr_fill(const int* __restrict__ src, const int* __restrict__ dst,
                         int* __restrict__ cur, int* __restrict__ cidx, int e) {
    int i = blockIdx.x * 256 + threadIdx.x;
    if (i >= e) return;
    int p = atomicAdd(&cur[dst[i]], 1);
    cidx[p] = src[i];
}

// scatter combined pair list into src-sorted order; so[] = global output slot
__global__ void sort_fill(const int* __restrict__ ps, const int* __restrict__ pd,
                          const int* __restrict__ ns, const int* __restrict__ nd,
                          int ep, int te, int* __restrict__ cur,
                          int* __restrict__ se, int* __restrict__ sd,
                          int* __restrict__ so) {
    int i = blockIdx.x * 256 + threadIdx.x;
    if (i >= te) return;
    int s, d;
    if (i < ep) { s = ps[i]; d = pd[i]; }
    else        { s = ns[i - ep]; d = nd[i - ep]; }
    int p = atomicAdd(&cur[s], 1);
    se[p] = s; sd[p] = d; so[p] = i;
}

// ---- dedicated mean-aggregation kernel: M[d] = mean over neighbors of X ----
// No LDS, no barriers, low VGPR -> max occupancy; latency hidden by TLP.
// One 16-lane group per dst row (16B/lane = full 128-col bf16 row).
__global__ __launch_bounds__(256, 8) void agg_mean(
    const u16* __restrict__ X, const int* __restrict__ rowptr,
    const int* __restrict__ cidx, u16* __restrict__ M, int n) {
    const int t = threadIdx.x;
    const int row = blockIdx.x * 16 + (t >> 4);
    if (row >= n) return;
    const int colo = (t & 15) * 8;
    const int s0 = rowptr[row], s1 = rowptr[row + 1];
    float a[8] = {0.f, 0.f, 0.f, 0.f, 0.f, 0.f, 0.f, 0.f};
    int i = s0;
    for (; i + 3 < s1; i += 4) {
        int c0 = cidx[i], c1 = cidx[i + 1], c2 = cidx[i + 2], c3 = cidx[i + 3];
        uint4 v0 = *(const uint4*)(X + (size_t)c0 * HD + colo);
        uint4 v1 = *(const uint4*)(X + (size_t)c1 * HD + colo);
        uint4 v2 = *(const uint4*)(X + (size_t)c2 * HD + colo);
        uint4 v3 = *(const uint4*)(X + (size_t)c3 * HD + colo);
        acc8_bf16(v0, a); acc8_bf16(v1, a);
        acc8_bf16(v2, a); acc8_bf16(v3, a);
    }
    if (i + 1 < s1) {
        int c0 = cidx[i], c1 = cidx[i + 1];
        uint4 v0 = *(const uint4*)(X + (size_t)c0 * HD + colo);
        uint4 v1 = *(const uint4*)(X + (size_t)c1 * HD + colo);
        acc8_bf16(v0, a); acc8_bf16(v1, a);
        i += 2;
    }
    if (i < s1) {
        uint4 v0 = *(const uint4*)(X + (size_t)cidx[i] * HD + colo);
        acc8_bf16(v0, a);
    }
    float iv = 1.f / fmaxf((float)(s1 - s0), 1.f);
    uint4 o;
    o.x = pk2bf(a[0] * iv, a[1] * iv);
    o.y = pk2bf(a[2] * iv, a[3] * iv);
    o.z = pk2bf(a[4] * iv, a[5] * iv);
    o.w = pk2bf(a[6] * iv, a[7] * iv);
    *(uint4*)(M + (size_t)row * HD + colo) = o;
}

// ---- streaming SAGE GEMM: hout = [relu](X@Ws + M@Wn + b), in-place safe ----
// (block touches only its own 64 rows of X/M/hout; X may alias hout)
template <bool RELU>
__global__ __launch_bounds__(256, 4) void sage_gemm(
    const u16* __restrict__ X, const u16* __restrict__ M,
    const u16* __restrict__ Wsp, const u16* __restrict__ Wnp,
    const void* __restrict__ bias, u16* __restrict__ hout,
    const int* __restrict__ gmode, int n) {
    __shared__ u16 zx[64 * 128];   // X tile (swizzled), 16 KB
    __shared__ u16 zm[64 * 128];   // M tile (swizzled), 16 KB
    const bool f32m = gmode[0] != 0;
    const int t = threadIdx.x;
    const int n0 = blockIdx.x * 64;
    const int lane = t & 63;
    const int w = t >> 6;
    const int cl = lane & 15, quad = lane >> 4;

    // ---- stage both tiles (8 x 16B loads in flight per thread) ----
    #pragma unroll
    for (int i = 0; i < 4; i++) {
        int idx = t + i * 256;
        int e = idx >> 4, sg = (idx & 15) * 8;
        int node = n0 + e;
        uint4 px = make_uint4(0, 0, 0, 0), pm = make_uint4(0, 0, 0, 0);
        if (node < n) {
            px = *(const uint4*)(X + (size_t)node * HD + sg);
            pm = *(const uint4*)(M + (size_t)node * HD + sg);
        }
        *(uint4*)&zx[swz(e, sg)] = px;
        *(uint4*)&zm[swz(e, sg)] = pm;
    }
    __syncthreads();

    f32x4 acc[2][4];
    #pragma unroll
    for (int ft = 0; ft < 2; ft++) {
        int f0 = w * 32 + ft * 16 + quad * 4;
        f32x4 bv;
        bv[0] = ldf(bias, f0 + 0, f32m);
        bv[1] = ldf(bias, f0 + 1, f32m);
        bv[2] = ldf(bias, f0 + 2, f32m);
        bv[3] = ldf(bias, f0 + 3, f32m);
        #pragma unroll
        for (int et = 0; et < 4; et++) acc[ft][et] = bv;
    }
    // ---- gemm: X@Ws ----
    #pragma unroll
    for (int ks = 0; ks < 4; ks++) {
        short8 a[2], b[4];
        #pragma unroll
        for (int ft = 0; ft < 2; ft++)
            a[ft] = ((const short8*)Wsp)[((w * 2 + ft) * 4 + ks) * 64 + lane];
        #pragma unroll
        for (int et = 0; et < 4; et++)
            b[et] = *(const short8*)&zx[swz(et * 16 + cl, ks * 32 + quad * 8)];
        #pragma unroll
        for (int ft = 0; ft < 2; ft++)
            #pragma unroll
            for (int et = 0; et < 4; et++)
                acc[ft][et] = __builtin_amdgcn_mfma_f32_16x16x32_bf16(
                    a[ft], b[et], acc[ft][et], 0, 0, 0);
    }
    // ---- gemm: M@Wn (same accumulator) ----
    #pragma unroll
    for (int ks = 0; ks < 4; ks++) {
        short8 a[2], b[4];
        #pragma unroll
        for (int ft = 0; ft < 2; ft++)
            a[ft] = ((const short8*)Wnp)[((w * 2 + ft) * 4 + ks) * 64 + lane];
        #pragma unroll
        for (int et = 0; et < 4; et++)
            b[et] = *(const short8*)&zm[swz(et * 16 + cl, ks * 32 + quad * 8)];
        #pragma unroll
        for (int ft = 0; ft < 2; ft++)
            #pragma unroll
            for (int et = 0; et < 4; et++)
                acc[ft][et] = __builtin_amdgcn_mfma_f32_16x16x32_bf16(
                    a[ft], b[et], acc[ft][et], 0, 0, 0);
    }
    __syncthreads();   // all tile reads done before epilogue aliases zx

    // ---- epilogue: packed b64 swizzled LDS writes, coalesced global copy ----
    #pragma unroll
    for (int ft = 0; ft < 2; ft++) {
        int f0 = w * 32 + ft * 16 + quad * 4;
        #pragma unroll
        for (int et = 0; et < 4; et++) {
            f32x4 v = acc[ft][et];
            float v0 = RELU ? fmaxf(v[0], 0.f) : v[0];
            float v1 = RELU ? fmaxf(v[1], 0.f) : v[1];
            float v2 = RELU ? fmaxf(v[2], 0.f) : v[2];
            float v3 = RELU ? fmaxf(v[3], 0.f) : v[3];
            *(uint2*)&zx[swz(et * 16 + cl, f0)] =
                make_uint2(pk2bf(v0, v1), pk2bf(v2, v3));
        }
    }
    __syncthreads();
    #pragma unroll
    for (int i = 0; i < 4; i++) {
        int idx = t + i * 256;
        int e = idx >> 4, sg = (idx & 15) * 8;
        int node = n0 + e;
        if (node < n)
            *(uint4*)&hout[(size_t)node * HD + sg] = *(const uint4*)&zx[swz(e, sg)];
    }
}

// ---- MFMA edge decoder on the SRC-SORTED combined pair list ----
// Exact round-2-proven structure (one tile/block, __syncthreads everywhere,
// weights loaded from L2 inside the gemm loops). Only change: edges come
// from se/sd (sorted by source node -> s-side rows are L1/L2-hot within a
// tile), and the scalar result is scattered to out[so[eg]].
__global__ __launch_bounds__(256) void edge_decode_mfma(
    const u16* __restrict__ h,
    const int* __restrict__ se, const int* __restrict__ sd,
    const int* __restrict__ so, int te,
    const u16* __restrict__ W1p, const void* __restrict__ b1,
    const u16* __restrict__ W2p, const void* __restrict__ b2,
    const void* __restrict__ W3, const void* __restrict__ b3,
    void* __restrict__ out, const int* __restrict__ gmode) {
    __shared__ u16 zA[64 * 128];
    __shared__ float psum[256];
    const bool f32m = gmode[0] != 0;
    const int t = threadIdx.x;
    const int e0 = blockIdx.x * 64;
    const int lane = t & 63;
    const int w = t >> 6;
    const int cl = lane & 15, quad = lane >> 4;

    // ---- stage z0 = bf16(h[s]*h[d]): 16 B/lane, packed bf16 mul ----
    #pragma unroll
    for (int i = 0; i < 4; i++) {
        int idx = t + i * 256;
        int e = idx >> 4, sg = (idx & 15) * 8;
        int eg = e0 + e;
        uint4 z = make_uint4(0, 0, 0, 0);
        if (eg < te) {
            int s = se[eg], d = sd[eg];
            uint4 a  = *(const uint4*)(h + (size_t)s * HD + sg);
            uint4 bv = *(const uint4*)(h + (size_t)d * HD + sg);
            z.x = hmul2(a.x, bv.x); z.y = hmul2(a.y, bv.y);
            z.z = hmul2(a.z, bv.z); z.w = hmul2(a.w, bv.w);
        }
        *(uint4*)&zA[swz(e, sg)] = z;
    }
    __syncthreads();

    // ---- gemm1: acc in registers ----
    f32x4 acc[2][4];
    #pragma unroll
    for (int ft = 0; ft < 2; ft++) {
        int f0 = w * 32 + ft * 16 + quad * 4;
        f32x4 bv;
        bv[0] = ldf(b1, f0 + 0, f32m);
        bv[1] = ldf(b1, f0 + 1, f32m);
        bv[2] = ldf(b1, f0 + 2, f32m);
        bv[3] = ldf(b1, f0 + 3, f32m);
        #pragma unroll
        for (int et = 0; et < 4; et++) acc[ft][et] = bv;
    }
    #pragma unroll
    for (int ks = 0; ks < 4; ks++) {
        short8 a[2], bb[4];
        #pragma unroll
        for (int ft = 0; ft < 2; ft++)
            a[ft] = ((const short8*)W1p)[((w * 2 + ft) * 4 + ks) * 64 + lane];
        #pragma unroll
        for (int et = 0; et < 4; et++)
            bb[et] = *(const short8*)&zA[swz(et * 16 + cl, ks * 32 + quad * 8)];
        #pragma unroll
        for (int ft = 0; ft < 2; ft++)
            #pragma unroll
            for (int et = 0; et < 4; et++)
                acc[ft][et] = __builtin_amdgcn_mfma_f32_16x16x32_bf16(
                    a[ft], bb[et], acc[ft][et], 0, 0, 0);
    }
    __syncthreads();   // all reads of z0 done

    // ---- write relu(z1) back into the SAME tile ----
    #pragma unroll
    for (int ft = 0; ft < 2; ft++) {
        int f0 = w * 32 + ft * 16 + quad * 4;
        #pragma unroll
        for (int et = 0; et < 4; et++) {
            f32x4 v = acc[ft][et];
            *(uint2*)&zA[swz(et * 16 + cl, f0)] = make_uint2(
                pk2bf(fmaxf(v[0], 0.f), fmaxf(v[1], 0.f)),
                pk2bf(fmaxf(v[2], 0.f), fmaxf(v[3], 0.f)));
        }
    }
    __syncthreads();

    // ---- gemm2 in registers + W3 dot ----
    #pragma unroll
    for (int ft = 0; ft < 2; ft++) {
        int f0 = w * 32 + ft * 16 + quad * 4;
        f32x4 bv;
        bv[0] = ldf(b2, f0 + 0, f32m);
        bv[1] = ldf(b2, f0 + 1, f32m);
        bv[2] = ldf(b2, f0 + 2, f32m);
        bv[3] = ldf(b2, f0 + 3, f32m);
        #pragma unroll
        for (int et = 0; et < 4; et++) acc[ft][et] = bv;
    }
    #pragma unroll
    for (int ks = 0; ks < 4; ks++) {
        short8 a[2], bb[4];
        #pragma unroll
        for (int ft = 0; ft < 2; ft++)
            a[ft] = ((const short8*)W2p)[((w * 2 + ft) * 4 + ks) * 64 + lane];
        #pragma unroll
        for (int et = 0; et < 4; et++)
            bb[et] = *(const short8*)&zA[swz(et * 16 + cl, ks * 32 + quad * 8)];
        #pragma unroll
        for (int ft = 0; ft < 2; ft++)
            #pragma unroll
            for (int et = 0; et < 4; et++)
                acc[ft][et] = __builtin_amdgcn_mfma_f32_16x16x32_bf16(
                    a[ft], bb[et], acc[ft][et], 0, 0, 0);
    }
    // per-lane partial dot of relu(z2) with W3 over this lane's 8 feats
    float p[4] = {0.f, 0.f, 0.f, 0.f};
    #pragma unroll
    for (int ft = 0; ft < 2; ft++) {
        int f0 = w * 32 + ft * 16 + quad * 4;
        float w3v0 = ldf(W3, f0 + 0, f32m);
        float w3v1 = ldf(W3, f0 + 1, f32m);
        float w3v2 = ldf(W3, f0 + 2, f32m);
        float w3v3 = ldf(W3, f0 + 3, f32m);
        #pragma unroll
        for (int et = 0; et < 4; et++) {
            f32x4 v = acc[ft][et];
            p[et] = fmaf(fmaxf(v[0], 0.f), w3v0, p[et]);
            p[et] = fmaf(fmaxf(v[1], 0.f), w3v1, p[et]);
            p[et] = fmaf(fmaxf(v[2], 0.f), w3v2, p[et]);
            p[et] = fmaf(fmaxf(v[3], 0.f), w3v3, p[et]);
        }
    }
    #pragma unroll
    for (int et = 0; et < 4; et++) {
        p[et] += __shfl_xor(p[et], 16);
        p[et] += __shfl_xor(p[et], 32);
    }
    if (lane < 16) {
        #pragma unroll
        for (int et = 0; et < 4; et++)
            psum[w * 64 + et * 16 + lane] = p[et];
    }
    __syncthreads();
    if (t < 64) {
        int eg = e0 + t;
        if (eg < te) {
            float sum = ldf(b3, 0, f32m) + (psum[t] + psum[64 + t])
                      + (psum[128 + t] + psum[192 + t]);
            int oi = so[eg];
            if (f32m) ((float*)out)[oi] = sum;
            else      ((u16*)out)[oi]   = f2bf(sum);
        }
    }
}

extern "C" void kernel_launch(void* const* d_in, const int* in_sizes, int n_in,
                              void* d_out, int out_size, void* d_ws, size_t ws_size,
                              hipStream_t stream) {
    const void* x      = d_in[0];
    const int* src     = (const int*)d_in[1];
    const int* dst     = (const int*)d_in[2];
    const int* pos_src = (const int*)d_in[3];
    const int* pos_dst = (const int*)d_in[4];
    const int* neg_src = (const int*)d_in[5];
    const int* neg_dst = (const int*)d_in[6];
    const void* Ws0 = d_in[7];
    const void* Wn0 = d_in[8];
    const void* b0  = d_in[9];
    const void* Ws1 = d_in[10];
    const void* Wn1 = d_in[11];
    const void* b1  = d_in[12];
    const void* dW1 = d_in[13];
    const void* db1 = d_in[14];
    const void* dW2 = d_in[15];
    const void* db2 = d_in[16];
    const void* dW3 = d_in[17];
    const void* db3 = d_in[18];

    const int n  = in_sizes[0] / HD;
    const int e  = in_sizes[1];
    const int ep = in_sizes[3];
    const int en = in_sizes[5];
    const int NB = (n + 255) / 256;
    const int te = ep + en;
    const int TT = (te + 63) / 64;

    // ws layout:
    //   R1 [n*HD u16] : xb -> h1 -> h2 (in-place chain)
    //   R2 [n*HD u16] : m0 -> m1 (mean rows); after 2nd sage_gemm it is dead
    //                   and reused for the src-sorted pair list (sd|so|se,
    //                   3*te*4 B = 7.2 MB <= 25.6 MB)
    //   mode | rowptr | cur | cidx | bsum | packed W x6
    char* base = (char*)d_ws;
    u16* R1 = (u16*)d_ws;
    u16* R2 = R1 + (size_t)n * HD;
    size_t off = (size_t)n * HD * 4;
    int* mode = (int*)(base + off);      off += 16;
    int* rowptr = (int*)(base + off);    off += (size_t)(n + 1) * 4; off = (off + 15) & ~(size_t)15;
    int* cur = (int*)(base + off);       off += (size_t)n * 4;       off = (off + 15) & ~(size_t)15;
    int* cidx = (int*)(base + off);      off += (size_t)e * 4;       off = (off + 15) & ~(size_t)15;
    int* bsum = (int*)(base + off);      off += (size_t)NB * 4;      off = (off + 15) & ~(size_t)15;
    u16* Wpk  = (u16*)(base + off);      // order: dW1, dW2, Ws0, Wn0, Ws1, Wn1
    u16* W1p  = Wpk;
    u16* W2p  = Wpk + 16384;
    u16* Ws0p = Wpk + 2 * 16384;
    u16* Wn0p = Wpk + 3 * 16384;
    u16* Ws1p = Wpk + 4 * 16384;
    u16* Wn1p = Wpk + 5 * 16384;
    // sorted pair list in R2 space (alive only after sage_gemm<false>)
    int* sd_ = (int*)R2;
    int* so_ = sd_ + te;
    int* se_ = so_ + te;

    detect_mode<<<dim3(1), dim3(256), 0, stream>>>((const u32*)x, mode);

    // ---- CSR build (once) ----
    hipMemsetAsync(cur, 0, (size_t)n * 4, stream);   // cur doubles as cnt
    cnt_count<<<dim3((e + 255) / 256), dim3(256), 0, stream>>>(dst, cur, e);
    scan_blocks<<<dim3(NB), dim3(256), 0, stream>>>(cur, rowptr, bsum, n);
    scan_bsum<<<dim3(1), dim3(1024), 0, stream>>>(bsum, NB);
    scan_add<<<dim3((n + 256) / 256), dim3(256), 0, stream>>>(rowptr, bsum, cur, n, e);
    csr_fill<<<dim3((e + 255) / 256), dim3(256), 0, stream>>>(src, dst, cur, cidx, e);

    pack_w6<<<dim3(384), dim3(256), 0, stream>>>(dW1, dW2, Ws0, Wn0, Ws1, Wn1, Wpk, mode);

    // ---- bf16 X materialized into R1 (convert or copy) ----
    cast_x<<<dim3(2048), dim3(256), 0, stream>>>(x, R1, mode, n * (HD / 8));

    // ---- layer 0: m0 = mean_agg(xb); h1 = relu(xb@Ws0 + m0@Wn0 + b0) ----
    agg_mean<<<dim3((n + 15) / 16), dim3(256), 0, stream>>>(R1, rowptr, cidx, R2, n);
    sage_gemm<true><<<dim3((n + 63) / 64), dim3(256), 0, stream>>>(
        R1, R2, Ws0p, Wn0p, b0, R1, mode, n);

    // ---- layer 1: m1 = mean_agg(h1); h2 = h1@Ws1 + m1@Wn1 + b1 ----
    agg_mean<<<dim3((n + 15) / 16), dim3(256), 0, stream>>>(R1, rowptr, cidx, R2, n);
    sage_gemm<false><<<dim3((n + 63) / 64), dim3(256), 0, stream>>>(
        R1, R2, Ws1p, Wn1p, b1, R1, mode, n);

    // ---- sort combined pair list by src (reuses CSR machinery; R2 dead) ----
    hipMemsetAsync(cur, 0, (size_t)n * 4, stream);
    cnt2_count<<<dim3((te + 255) / 256), dim3(256), 0, stream>>>(
        pos_src, neg_src, ep, te, cur);
    scan_blocks<<<dim3(NB), dim3(256), 0, stream>>>(cur, rowptr, bsum, n);
    scan_bsum<<<dim3(1), dim3(1024), 0, stream>>>(bsum, NB);
    scan_add<<<dim3((n + 256) / 256), dim3(256), 0, stream>>>(rowptr, bsum, cur, n, te);
    sort_fill<<<dim3((te + 255) / 256), dim3(256), 0, stream>>>(
        pos_src, pos_dst, neg_src, neg_dst, ep, te, cur, se_, sd_, so_);

    // ---- fused pos+neg decoder on h2 (bf16, = R1), src-sorted edges ----
    edge_decode_mfma<<<dim3(TT), dim3(256), 0, stream>>>(
        R1, se_, sd_, so_, te,
        W1p, db1, W2p, db2, dW3, db3, d_out, mode);
}

// Round 8
// 342.961 us; speedup vs baseline: 1.2212x; 1.2212x over previous
//
#include <hip/hip_runtime.h>
#include <hip/hip_bf16.h>

#define HD 128

typedef unsigned int u32;
typedef unsigned short u16;
typedef __attribute__((ext_vector_type(8))) short short8;   // 8 bf16 (4 VGPRs)
typedef __attribute__((ext_vector_type(4))) float f32x4;    // MFMA C/D

__device__ __forceinline__ float bf2f(u16 u) {
    return __uint_as_float(((u32)u) << 16);
}
__device__ __forceinline__ u16 f2bf(float f) {
    u32 u = __float_as_uint(f);
    u32 r = (u + 0x7fffu + ((u >> 16) & 1u)) >> 16;   // RNE
    return (u16)r;
}
// packed RNE f32x2 -> bf16x2; lo -> low 16 bits
__device__ __forceinline__ u32 pk2bf(float lo, float hi) {
    __hip_bfloat162 h = __float22bfloat162_rn(make_float2(lo, hi));
    union { __hip_bfloat162 h; u32 u; } cv; cv.h = h;
    return cv.u;
}
// packed bf16x2 multiply (RNE)
__device__ __forceinline__ u32 hmul2(u32 a, u32 b) {
    union { u32 u; __hip_bfloat162 h; } x, y, r;
    x.u = a; y.u = b;
    r.h = __hmul2(x.h, y.h);
    return r.u;
}
__device__ __forceinline__ float ldf(const void* p, size_t i, bool f32m) {
    return f32m ? ((const float*)p)[i] : bf2f(((const u16*)p)[i]);
}
// XOR-swizzled halfword index into a 64x128 bf16 LDS tile (16B-block swizzle).
__device__ __forceinline__ int swz(int row, int col) {
    return row * 128 + ((((col >> 3) ^ (row & 7)) << 3) | (col & 7));
}
__device__ __forceinline__ void acc8_bf16(uint4 v, float* a) {
    a[0] += __uint_as_float(v.x << 16); a[1] += __uint_as_float(v.x & 0xffff0000u);
    a[2] += __uint_as_float(v.y << 16); a[3] += __uint_as_float(v.y & 0xffff0000u);
    a[4] += __uint_as_float(v.z << 16); a[5] += __uint_as_float(v.z & 0xffff0000u);
    a[6] += __uint_as_float(v.w << 16); a[7] += __uint_as_float(v.w & 0xffff0000u);
}

// ---- dtype detector (parallel) ----
__global__ void detect_mode(const u32* __restrict__ x, int* __restrict__ mode) {
    __shared__ int cnt_s;
    if (threadIdx.x == 0) cnt_s = 0;
    __syncthreads();
    u32 e = (x[threadIdx.x] >> 23) & 0xFFu;
    if (e >= 90u && e < 170u) atomicAdd(&cnt_s, 1);
    __syncthreads();
    if (threadIdx.x == 0) mode[0] = (cnt_s >= 128) ? 1 : 0;
}

// ---- materialize bf16 X into workspace (convert f32, or plain copy bf16) ----
__global__ void cast_x(const void* __restrict__ x, u16* __restrict__ xb,
                       const int* __restrict__ gmode, int total8) {
    const bool f32m = gmode[0] != 0;
    int i = blockIdx.x * 256 + threadIdx.x;
    int stride = gridDim.x * 256;
    if (f32m) {
        for (; i < total8; i += stride) {
            const float* p = (const float*)x + (size_t)i * 8;
            float4 v0 = *(const float4*)p, v1 = *(const float4*)(p + 4);
            uint4 o;
            o.x = pk2bf(v0.x, v0.y); o.y = pk2bf(v0.z, v0.w);
            o.z = pk2bf(v1.x, v1.y); o.w = pk2bf(v1.z, v1.w);
            *(uint4*)(xb + (size_t)i * 8) = o;
        }
    } else {
        for (; i < total8; i += stride) {
            *(uint4*)(xb + (size_t)i * 8) =
                *(const uint4*)((const u16*)x + (size_t)i * 8);
        }
    }
}

// ---- pack six 128x128 weight matrices into MFMA fragment order (bf16) ----
__global__ void pack_w6(const void* __restrict__ W0, const void* __restrict__ W1,
                        const void* __restrict__ W2, const void* __restrict__ W3,
                        const void* __restrict__ W4, const void* __restrict__ W5,
                        u16* __restrict__ out, const int* __restrict__ gmode) {
    const bool f32m = gmode[0] != 0;
    int gid = blockIdx.x * 256 + threadIdx.x;
    if (gid >= 6 * 16384) return;
    int sel = gid >> 14, idx = gid & 16383;
    const void* W = sel == 0 ? W0 : sel == 1 ? W1 : sel == 2 ? W2 :
                    sel == 3 ? W3 : sel == 4 ? W4 : W5;
    int j = idx & 7, lane = (idx >> 3) & 63, ks = (idx >> 9) & 3, nt = idx >> 11;
    int k = ks * 32 + (lane >> 4) * 8 + j;
    int n = nt * 16 + (lane & 15);
    out[gid] = f2bf(ldf(W, (size_t)k * HD + n, f32m));
}

// ================= CSR build ===========
__global__ void cnt_count(const int* __restrict__ dst, int* __restrict__ cnt, int e) {
    int i = blockIdx.x * 256 + threadIdx.x;
    if (i < e) atomicAdd(&cnt[dst[i]], 1);
}

__global__ void scan_blocks(const int* __restrict__ cnt, int* __restrict__ rowptr,
                            int* __restrict__ bsum, int n) {
    __shared__ int s[256];
    int t = threadIdx.x, gid = blockIdx.x * 256 + t;
    int v = (gid < n) ? cnt[gid] : 0;
    s[t] = v; __syncthreads();
    #pragma unroll
    for (int off = 1; off < 256; off <<= 1) {
        int x = (t >= off) ? s[t - off] : 0;
        __syncthreads();
        s[t] += x;
        __syncthreads();
    }
    if (gid < n) rowptr[gid] = s[t] - v;
    if (t == 255) bsum[blockIdx.x] = s[255];
}

__global__ void scan_bsum(int* __restrict__ bsum, int nb) {
    __shared__ int s[1024];
    __shared__ int carry;
    int t = threadIdx.x;
    if (t == 0) carry = 0;
    __syncthreads();
    for (int base = 0; base < nb; base += 1024) {
        int i = base + t;
        int v = (i < nb) ? bsum[i] : 0;
        s[t] = v; __syncthreads();
        #pragma unroll
        for (int off = 1; off < 1024; off <<= 1) {
            int x = (t >= off) ? s[t - off] : 0;
            __syncthreads();
            s[t] += x;
            __syncthreads();
        }
        if (i < nb) bsum[i] = carry + s[t] - v;
        __syncthreads();
        if (t == 0) carry += s[1023];
        __syncthreads();
    }
}

// rowptr finalize + cursor init (cur = rowptr)
__global__ void scan_add(int* __restrict__ rowptr, const int* __restrict__ bsum,
                         int* __restrict__ cur, int n, int e) {
    int gid = blockIdx.x * 256 + threadIdx.x;
    if (gid < n) {
        int v = rowptr[gid] + bsum[blockIdx.x];
        rowptr[gid] = v;
        cur[gid] = v;
    } else if (gid == n) {
        rowptr[n] = e;
    }
}

__global__ void csr_fill(const int* __restrict__ src, const int* __restrict__ dst,
                         int* __restrict__ cur, int* __restrict__ cidx, int e) {
    int i = blockIdx.x * 256 + threadIdx.x;
    if (i >= e) return;
    int p = atomicAdd(&cur[dst[i]], 1);
    cidx[p] = src[i];
}

// ---- dedicated mean-aggregation kernel: M[d] = mean over neighbors of X ----
// No LDS, no barriers, low VGPR -> max occupancy; latency hidden by TLP.
// One 16-lane group per dst row (16B/lane = full 128-col bf16 row).
__global__ __launch_bounds__(256, 8) void agg_mean(
    const u16* __restrict__ X, const int* __restrict__ rowptr,
    const int* __restrict__ cidx, u16* __restrict__ M, int n) {
    const int t = threadIdx.x;
    const int row = blockIdx.x * 16 + (t >> 4);
    if (row >= n) return;
    const int colo = (t & 15) * 8;
    const int s0 = rowptr[row], s1 = rowptr[row + 1];
    float a[8] = {0.f, 0.f, 0.f, 0.f, 0.f, 0.f, 0.f, 0.f};
    int i = s0;
    for (; i + 3 < s1; i += 4) {
        int c0 = cidx[i], c1 = cidx[i + 1], c2 = cidx[i + 2], c3 = cidx[i + 3];
        uint4 v0 = *(const uint4*)(X + (size_t)c0 * HD + colo);
        uint4 v1 = *(const uint4*)(X + (size_t)c1 * HD + colo);
        uint4 v2 = *(const uint4*)(X + (size_t)c2 * HD + colo);
        uint4 v3 = *(const uint4*)(X + (size_t)c3 * HD + colo);
        acc8_bf16(v0, a); acc8_bf16(v1, a);
        acc8_bf16(v2, a); acc8_bf16(v3, a);
    }
    if (i + 1 < s1) {
        int c0 = cidx[i], c1 = cidx[i + 1];
        uint4 v0 = *(const uint4*)(X + (size_t)c0 * HD + colo);
        uint4 v1 = *(const uint4*)(X + (size_t)c1 * HD + colo);
        acc8_bf16(v0, a); acc8_bf16(v1, a);
        i += 2;
    }
    if (i < s1) {
        uint4 v0 = *(const uint4*)(X + (size_t)cidx[i] * HD + colo);
        acc8_bf16(v0, a);
    }
    float iv = 1.f / fmaxf((float)(s1 - s0), 1.f);
    uint4 o;
    o.x = pk2bf(a[0] * iv, a[1] * iv);
    o.y = pk2bf(a[2] * iv, a[3] * iv);
    o.z = pk2bf(a[4] * iv, a[5] * iv);
    o.w = pk2bf(a[6] * iv, a[7] * iv);
    *(uint4*)(M + (size_t)row * HD + colo) = o;
}

// ---- streaming SAGE GEMM: hout = [relu](X@Ws + M@Wn + b), in-place safe ----
// (block touches only its own 64 rows of X/M/hout; X may alias hout)
template <bool RELU>
__global__ __launch_bounds__(256, 4) void sage_gemm(
    const u16* __restrict__ X, const u16* __restrict__ M,
    const u16* __restrict__ Wsp, const u16* __restrict__ Wnp,
    const void* __restrict__ bias, u16* __restrict__ hout,
    const int* __restrict__ gmode, int n) {
    __shared__ u16 zx[64 * 128];   // X tile (swizzled), 16 KB
    __shared__ u16 zm[64 * 128];   // M tile (swizzled), 16 KB
    const bool f32m = gmode[0] != 0;
    const int t = threadIdx.x;
    const int n0 = blockIdx.x * 64;
    const int lane = t & 63;
    const int w = t >> 6;
    const int cl = lane & 15, quad = lane >> 4;

    // ---- stage both tiles (8 x 16B loads in flight per thread) ----
    #pragma unroll
    for (int i = 0; i < 4; i++) {
        int idx = t + i * 256;
        int e = idx >> 4, sg = (idx & 15) * 8;
        int node = n0 + e;
        uint4 px = make_uint4(0, 0, 0, 0), pm = make_uint4(0, 0, 0, 0);
        if (node < n) {
            px = *(const uint4*)(X + (size_t)node * HD + sg);
            pm = *(const uint4*)(M + (size_t)node * HD + sg);
        }
        *(uint4*)&zx[swz(e, sg)] = px;
        *(uint4*)&zm[swz(e, sg)] = pm;
    }
    __syncthreads();

    f32x4 acc[2][4];
    #pragma unroll
    for (int ft = 0; ft < 2; ft++) {
        int f0 = w * 32 + ft * 16 + quad * 4;
        f32x4 bv;
        bv[0] = ldf(bias, f0 + 0, f32m);
        bv[1] = ldf(bias, f0 + 1, f32m);
        bv[2] = ldf(bias, f0 + 2, f32m);
        bv[3] = ldf(bias, f0 + 3, f32m);
        #pragma unroll
        for (int et = 0; et < 4; et++) acc[ft][et] = bv;
    }
    // ---- gemm: X@Ws ----
    #pragma unroll
    for (int ks = 0; ks < 4; ks++) {
        short8 a[2], b[4];
        #pragma unroll
        for (int ft = 0; ft < 2; ft++)
            a[ft] = ((const short8*)Wsp)[((w * 2 + ft) * 4 + ks) * 64 + lane];
        #pragma unroll
        for (int et = 0; et < 4; et++)
            b[et] = *(const short8*)&zx[swz(et * 16 + cl, ks * 32 + quad * 8)];
        #pragma unroll
        for (int ft = 0; ft < 2; ft++)
            #pragma unroll
            for (int et = 0; et < 4; et++)
                acc[ft][et] = __builtin_amdgcn_mfma_f32_16x16x32_bf16(
                    a[ft], b[et], acc[ft][et], 0, 0, 0);
    }
    // ---- gemm: M@Wn (same accumulator) ----
    #pragma unroll
    for (int ks = 0; ks < 4; ks++) {
        short8 a[2], b[4];
        #pragma unroll
        for (int ft = 0; ft < 2; ft++)
            a[ft] = ((const short8*)Wnp)[((w * 2 + ft) * 4 + ks) * 64 + lane];
        #pragma unroll
        for (int et = 0; et < 4; et++)
            b[et] = *(const short8*)&zm[swz(et * 16 + cl, ks * 32 + quad * 8)];
        #pragma unroll
        for (int ft = 0; ft < 2; ft++)
            #pragma unroll
            for (int et = 0; et < 4; et++)
                acc[ft][et] = __builtin_amdgcn_mfma_f32_16x16x32_bf16(
                    a[ft], b[et], acc[ft][et], 0, 0, 0);
    }
    __syncthreads();   // all tile reads done before epilogue aliases zx

    // ---- epilogue: packed b64 swizzled LDS writes, coalesced global copy ----
    #pragma unroll
    for (int ft = 0; ft < 2; ft++) {
        int f0 = w * 32 + ft * 16 + quad * 4;
        #pragma unroll
        for (int et = 0; et < 4; et++) {
            f32x4 v = acc[ft][et];
            float v0 = RELU ? fmaxf(v[0], 0.f) : v[0];
            float v1 = RELU ? fmaxf(v[1], 0.f) : v[1];
            float v2 = RELU ? fmaxf(v[2], 0.f) : v[2];
            float v3 = RELU ? fmaxf(v[3], 0.f) : v[3];
            *(uint2*)&zx[swz(et * 16 + cl, f0)] =
                make_uint2(pk2bf(v0, v1), pk2bf(v2, v3));
        }
    }
    __syncthreads();
    #pragma unroll
    for (int i = 0; i < 4; i++) {
        int idx = t + i * 256;
        int e = idx >> 4, sg = (idx & 15) * 8;
        int node = n0 + e;
        if (node < n)
            *(uint4*)&hout[(size_t)node * HD + sg] = *(const uint4*)&zx[swz(e, sg)];
    }
}

// ---- MFMA edge decoder, pos+neg fused; ONE tile (17.4 KB, 8 blocks/CU) ----
// Proven-optimal config for this latency-bound kernel: 48 VGPR, ~49% occ,
// weights re-read from hot L2 inside the gemm loops (hoisting them costs
// occupancy and loses more than it gains — measured rounds 3/5).
__global__ __launch_bounds__(256) void edge_decode_mfma(
    const u16* __restrict__ h,
    const int* __restrict__ psrc, const int* __restrict__ pdst, int ep, int PB,
    const int* __restrict__ nsrc, const int* __restrict__ ndst, int en,
    const u16* __restrict__ W1p, const void* __restrict__ b1,
    const u16* __restrict__ W2p, const void* __restrict__ b2,
    const void* __restrict__ W3, const void* __restrict__ b3,
    void* __restrict__ out, const int* __restrict__ gmode) {
    __shared__ u16 zA[64 * 128];
    __shared__ float psum[256];
    const bool f32m = gmode[0] != 0;
    const int t = threadIdx.x;
    const int b = blockIdx.x;
    const int* esrc; const int* edst; int e0, obase, ne;
    if (b < PB) { esrc = psrc; edst = pdst; e0 = b * 64;        obase = 0;  ne = ep; }
    else        { esrc = nsrc; edst = ndst; e0 = (b - PB) * 64; obase = ep; ne = en; }
    const int lane = t & 63;
    const int w = t >> 6;
    const int cl = lane & 15, quad = lane >> 4;

    // ---- stage z0 = bf16(h[s]*h[d]): 16 B/lane, packed bf16 mul ----
    #pragma unroll
    for (int i = 0; i < 4; i++) {
        int idx = t + i * 256;
        int e = idx >> 4, sg = (idx & 15) * 8;
        int eg = e0 + e;
        uint4 z = make_uint4(0, 0, 0, 0);
        if (eg < ne) {
            int s = esrc[eg], d = edst[eg];
            uint4 a  = *(const uint4*)(h + (size_t)s * HD + sg);
            uint4 bv = *(const uint4*)(h + (size_t)d * HD + sg);
            z.x = hmul2(a.x, bv.x); z.y = hmul2(a.y, bv.y);
            z.z = hmul2(a.z, bv.z); z.w = hmul2(a.w, bv.w);
        }
        *(uint4*)&zA[swz(e, sg)] = z;
    }
    __syncthreads();

    // ---- gemm1: acc in registers ----
    f32x4 acc[2][4];
    #pragma unroll
    for (int ft = 0; ft < 2; ft++) {
        int f0 = w * 32 + ft * 16 + quad * 4;
        f32x4 bv;
        bv[0] = ldf(b1, f0 + 0, f32m);
        bv[1] = ldf(b1, f0 + 1, f32m);
        bv[2] = ldf(b1, f0 + 2, f32m);
        bv[3] = ldf(b1, f0 + 3, f32m);
        #pragma unroll
        for (int et = 0; et < 4; et++) acc[ft][et] = bv;
    }
    #pragma unroll
    for (int ks = 0; ks < 4; ks++) {
        short8 a[2], bb[4];
        #pragma unroll
        for (int ft = 0; ft < 2; ft++)
            a[ft] = ((const short8*)W1p)[((w * 2 + ft) * 4 + ks) * 64 + lane];
        #pragma unroll
        for (int et = 0; et < 4; et++)
            bb[et] = *(const short8*)&zA[swz(et * 16 + cl, ks * 32 + quad * 8)];
        #pragma unroll
        for (int ft = 0; ft < 2; ft++)
            #pragma unroll
            for (int et = 0; et < 4; et++)
                acc[ft][et] = __builtin_amdgcn_mfma_f32_16x16x32_bf16(
                    a[ft], bb[et], acc[ft][et], 0, 0, 0);
    }
    __syncthreads();   // all reads of z0 done

    // ---- write relu(z1) back into the SAME tile ----
    #pragma unroll
    for (int ft = 0; ft < 2; ft++) {
        int f0 = w * 32 + ft * 16 + quad * 4;
        #pragma unroll
        for (int et = 0; et < 4; et++) {
            f32x4 v = acc[ft][et];
            *(uint2*)&zA[swz(et * 16 + cl, f0)] = make_uint2(
                pk2bf(fmaxf(v[0], 0.f), fmaxf(v[1], 0.f)),
                pk2bf(fmaxf(v[2], 0.f), fmaxf(v[3], 0.f)));
        }
    }
    __syncthreads();

    // ---- gemm2 in registers + W3 dot ----
    #pragma unroll
    for (int ft = 0; ft < 2; ft++) {
        int f0 = w * 32 + ft * 16 + quad * 4;
        f32x4 bv;
        bv[0] = ldf(b2, f0 + 0, f32m);
        bv[1] = ldf(b2, f0 + 1, f32m);
        bv[2] = ldf(b2, f0 + 2, f32m);
        bv[3] = ldf(b2, f0 + 3, f32m);
        #pragma unroll
        for (int et = 0; et < 4; et++) acc[ft][et] = bv;
    }
    #pragma unroll
    for (int ks = 0; ks < 4; ks++) {
        short8 a[2], bb[4];
        #pragma unroll
        for (int ft = 0; ft < 2; ft++)
            a[ft] = ((const short8*)W2p)[((w * 2 + ft) * 4 + ks) * 64 + lane];
        #pragma unroll
        for (int et = 0; et < 4; et++)
            bb[et] = *(const short8*)&zA[swz(et * 16 + cl, ks * 32 + quad * 8)];
        #pragma unroll
        for (int ft = 0; ft < 2; ft++)
            #pragma unroll
            for (int et = 0; et < 4; et++)
                acc[ft][et] = __builtin_amdgcn_mfma_f32_16x16x32_bf16(
                    a[ft], bb[et], acc[ft][et], 0, 0, 0);
    }
    // per-lane partial dot of relu(z2) with W3 over this lane's 8 feats
    float p[4] = {0.f, 0.f, 0.f, 0.f};
    #pragma unroll
    for (int ft = 0; ft < 2; ft++) {
        int f0 = w * 32 + ft * 16 + quad * 4;
        float w3v0 = ldf(W3, f0 + 0, f32m);
        float w3v1 = ldf(W3, f0 + 1, f32m);
        float w3v2 = ldf(W3, f0 + 2, f32m);
        float w3v3 = ldf(W3, f0 + 3, f32m);
        #pragma unroll
        for (int et = 0; et < 4; et++) {
            f32x4 v = acc[ft][et];
            p[et] = fmaf(fmaxf(v[0], 0.f), w3v0, p[et]);
            p[et] = fmaf(fmaxf(v[1], 0.f), w3v1, p[et]);
            p[et] = fmaf(fmaxf(v[2], 0.f), w3v2, p[et]);
            p[et] = fmaf(fmaxf(v[3], 0.f), w3v3, p[et]);
        }
    }
    #pragma unroll
    for (int et = 0; et < 4; et++) {
        p[et] += __shfl_xor(p[et], 16);
        p[et] += __shfl_xor(p[et], 32);
    }
    if (lane < 16) {
        #pragma unroll
        for (int et = 0; et < 4; et++)
            psum[w * 64 + et * 16 + lane] = p[et];
    }
    __syncthreads();
    if (t < 64) {
        int eg = e0 + t;
        if (eg < ne) {
            float sum = ldf(b3, 0, f32m) + (psum[t] + psum[64 + t])
                      + (psum[128 + t] + psum[192 + t]);
            if (f32m) ((float*)out)[obase + eg] = sum;
            else      ((u16*)out)[obase + eg]   = f2bf(sum);
        }
    }
}

extern "C" void kernel_launch(void* const* d_in, const int* in_sizes, int n_in,
                              void* d_out, int out_size, void* d_ws, size_t ws_size,
                              hipStream_t stream) {
    const void* x      = d_in[0];
    const int* src     = (const int*)d_in[1];
    const int* dst     = (const int*)d_in[2];
    const int* pos_src = (const int*)d_in[3];
    const int* pos_dst = (const int*)d_in[4];
    const int* neg_src = (const int*)d_in[5];
    const int* neg_dst = (const int*)d_in[6];
    const void* Ws0 = d_in[7];
    const void* Wn0 = d_in[8];
    const void* b0  = d_in[9];
    const void* Ws1 = d_in[10];
    const void* Wn1 = d_in[11];
    const void* b1  = d_in[12];
    const void* dW1 = d_in[13];
    const void* db1 = d_in[14];
    const void* dW2 = d_in[15];
    const void* db2 = d_in[16];
    const void* dW3 = d_in[17];
    const void* db3 = d_in[18];

    const int n  = in_sizes[0] / HD;
    const int e  = in_sizes[1];
    const int ep = in_sizes[3];
    const int en = in_sizes[5];
    const int NB = (n + 255) / 256;
    const int PB = (ep + 63) / 64, NDB = (en + 63) / 64;

    // ws layout:
    //   R1 [n*HD u16] : xb -> h1 -> h2 (in-place chain)
    //   R2 [n*HD u16] : m0 -> m1 (mean-aggregated rows)
    //   mode | rowptr | cur | cidx | bsum | packed W x6
    char* base = (char*)d_ws;
    u16* R1 = (u16*)d_ws;
    u16* R2 = R1 + (size_t)n * HD;
    size_t off = (size_t)n * HD * 4;
    int* mode = (int*)(base + off);      off += 16;
    int* rowptr = (int*)(base + off);    off += (size_t)(n + 1) * 4; off = (off + 15) & ~(size_t)15;
    int* cur = (int*)(base + off);       off += (size_t)n * 4;       off = (off + 15) & ~(size_t)15;
    int* cidx = (int*)(base + off);      off += (size_t)e * 4;       off = (off + 15) & ~(size_t)15;
    int* bsum = (int*)(base + off);      off += (size_t)NB * 4;      off = (off + 15) & ~(size_t)15;
    u16* Wpk  = (u16*)(base + off);      // order: dW1, dW2, Ws0, Wn0, Ws1, Wn1
    u16* W1p  = Wpk;
    u16* W2p  = Wpk + 16384;
    u16* Ws0p = Wpk + 2 * 16384;
    u16* Wn0p = Wpk + 3 * 16384;
    u16* Ws1p = Wpk + 4 * 16384;
    u16* Wn1p = Wpk + 5 * 16384;

    detect_mode<<<dim3(1), dim3(256), 0, stream>>>((const u32*)x, mode);

    // ---- CSR build (once) ----
    hipMemsetAsync(cur, 0, (size_t)n * 4, stream);   // cur doubles as cnt
    cnt_count<<<dim3((e + 255) / 256), dim3(256), 0, stream>>>(dst, cur, e);
    scan_blocks<<<dim3(NB), dim3(256), 0, stream>>>(cur, rowptr, bsum, n);
    scan_bsum<<<dim3(1), dim3(1024), 0, stream>>>(bsum, NB);
    scan_add<<<dim3((n + 256) / 256), dim3(256), 0, stream>>>(rowptr, bsum, cur, n, e);
    csr_fill<<<dim3((e + 255) / 256), dim3(256), 0, stream>>>(src, dst, cur, cidx, e);

    pack_w6<<<dim3(384), dim3(256), 0, stream>>>(dW1, dW2, Ws0, Wn0, Ws1, Wn1, Wpk, mode);

    // ---- bf16 X materialized into R1 (convert or copy) ----
    cast_x<<<dim3(2048), dim3(256), 0, stream>>>(x, R1, mode, n * (HD / 8));

    // ---- layer 0: m0 = mean_agg(xb); h1 = relu(xb@Ws0 + m0@Wn0 + b0) ----
    agg_mean<<<dim3((n + 15) / 16), dim3(256), 0, stream>>>(R1, rowptr, cidx, R2, n);
    sage_gemm<true><<<dim3((n + 63) / 64), dim3(256), 0, stream>>>(
        R1, R2, Ws0p, Wn0p, b0, R1, mode, n);

    // ---- layer 1: m1 = mean_agg(h1); h2 = h1@Ws1 + m1@Wn1 + b1 ----
    agg_mean<<<dim3((n + 15) / 16), dim3(256), 0, stream>>>(R1, rowptr, cidx, R2, n);
    sage_gemm<false><<<dim3((n + 63) / 64), dim3(256), 0, stream>>>(
        R1, R2, Ws1p, Wn1p, b1, R1, mode, n);

    // ---- fused pos+neg decoder on h2 (bf16, = R1) ----
    edge_decode_mfma<<<dim3(PB + NDB), dim3(256), 0, stream>>>(
        R1, pos_src, pos_dst, ep, PB, neg_src, neg_dst, en,
        W1p, db1, W2p, db2, dW3, db3, d_out, mode);
}